// Round 10
// baseline (455.518 us; speedup 1.0000x reference)
//
#include <hip/hip_runtime.h>
#include <hip/hip_bf16.h>
#include <stdint.h>

typedef __attribute__((ext_vector_type(4))) float f32x4;
typedef __attribute__((ext_vector_type(8))) short short8;

#define DIM_S 4096
#define DIM_IN 1536
#define DIM_OUT 3072
#define NB 8
#define NORG 4

#define XB_ELEMS (NB * DIM_S * DIM_IN)      /* 50331648 */
#define WT_ELEMS (NORG * DIM_OUT * DIM_IN)  /* 18874368 */
#define WS_NEED ((size_t)(XB_ELEMS + WT_ELEMS) * 2)

__device__ __forceinline__ unsigned short f2bf(float f) {
    union { __hip_bfloat16 h; unsigned short u; } c;
    c.h = __float2bfloat16(f);
    return c.u;
}

__device__ __forceinline__ void gload16(const void* g, void* l) {
    __builtin_amdgcn_global_load_lds(
        (const __attribute__((address_space(1))) unsigned int*)g,
        (__attribute__((address_space(3))) unsigned int*)l, 16, 0, 0);
}

// ---------- pass 1a: x f32 -> bf16 ----------
__global__ __launch_bounds__(256) void cvt_x(const float* __restrict__ x,
                                             unsigned short* __restrict__ xb) {
    const int nchunk = XB_ELEMS / 8;
    for (int c = blockIdx.x * 256 + threadIdx.x; c < nchunk; c += gridDim.x * 256) {
        const float4 v0 = *reinterpret_cast<const float4*>(x + (size_t)c * 8);
        const float4 v1 = *reinterpret_cast<const float4*>(x + (size_t)c * 8 + 4);
        union { unsigned short u[8]; short8 v; } p;
        p.u[0] = f2bf(v0.x); p.u[1] = f2bf(v0.y); p.u[2] = f2bf(v0.z); p.u[3] = f2bf(v0.w);
        p.u[4] = f2bf(v1.x); p.u[5] = f2bf(v1.y); p.u[6] = f2bf(v1.z); p.u[7] = f2bf(v1.w);
        *reinterpret_cast<short8*>(xb + (size_t)c * 8) = p.v;
    }
}

// ---------- pass 1b: W [org][K][N] f32 -> W^T [org][N][K] bf16 ----------
__global__ __launch_bounds__(256) void cvt_wt(const float* __restrict__ w,
                                              unsigned short* __restrict__ wt) {
    __shared__ unsigned short T[64][68];
    const int bid = blockIdx.x;
    const int org = bid / (24 * 48);
    const int rem = bid % (24 * 48);
    const int k0 = (rem / 48) * 64;
    const int n0 = (rem % 48) * 64;
    const float* __restrict__ wp = w + (size_t)org * DIM_IN * DIM_OUT;
    unsigned short* __restrict__ op = wt + (size_t)org * DIM_OUT * DIM_IN;
    const int t = threadIdx.x;
    #pragma unroll
    for (int i = 0; i < 4; ++i) {
        const int c = t + 256 * i;
        const int kk = c >> 4, nq = (c & 15) * 4;
        const float4 v = *reinterpret_cast<const float4*>(
            wp + (size_t)(k0 + kk) * DIM_OUT + n0 + nq);
        ushort4 pv;
        pv.x = f2bf(v.x); pv.y = f2bf(v.y); pv.z = f2bf(v.z); pv.w = f2bf(v.w);
        *reinterpret_cast<ushort4*>(&T[kk][nq]) = pv;
    }
    __syncthreads();
    #pragma unroll
    for (int i = 0; i < 2; ++i) {
        const int c = t + 256 * i;
        const int n = c >> 3, k8 = (c & 7) * 8;
        union { unsigned short u[8]; short8 v; } p;
        #pragma unroll
        for (int j = 0; j < 8; ++j) p.u[j] = T[k8 + j][n];
        *reinterpret_cast<short8*>(op + (size_t)(n0 + n) * DIM_IN + k0 + k8) = p.v;
    }
}

// ---------- pass 2: 256x128 tile, 4 waves, 3-buf 72KiB LDS, 2 blocks/CU ----------
// Per K-tile (BK=32): A slot [256][32] bf16 (16 KB), B slot [128][32] (8 KB).
// st_16x32 swizzle (R7, conflicts=0): phys quad p = q ^ (((row>>3)&1)<<1),
// applied on pre-swizzled global source + swizzled ds_read offsets.
// 3 buffers, staging 2 tiles ahead, per-wave vmcnt(6) counted (never 0).
// ONE raw s_barrier per K-tile: the staged buf (t+2)%3 was last read at t-1,
// and those reads complete before t-1's end barrier (lgkm precedes MFMA).
__global__ __launch_bounds__(256, 2) void mol_gemm_3b(
    const unsigned short* __restrict__ xb, const int* __restrict__ orgidx,
    const unsigned short* __restrict__ wt, const float* __restrict__ bias,
    float* __restrict__ out)
{
    __shared__ __align__(16) unsigned short LDS[3][12288];  // 72 KiB

    const int tid  = threadIdx.x;
    const int lane = tid & 63;
    const int wave = tid >> 6;     // 0..3
    const int wr = wave >> 1;      // 0..1  (M half, 128 rows)
    const int wc = wave & 1;       // 0..1  (N half, 64 cols)
    const int l15 = lane & 15;
    const int q16 = lane >> 4;

    // XCD-aware remap: 3072 blocks = 8 XCDs x 384; col-fastest; 1 batch/XCD.
    const int bid = blockIdx.x;
    const int id  = (bid & 7) * 384 + (bid >> 3);
    const int row0 = (id / 24) * 256;
    const int col0 = (id % 24) * 128;
    const int org  = orgidx[row0 >> 12];

    const unsigned short* __restrict__ Abase = xb + (size_t)row0 * DIM_IN;
    const unsigned short* __restrict__ Bbase =
        wt + (size_t)org * DIM_OUT * DIM_IN + (size_t)col0 * DIM_IN;

    // staging: chunk c = j*256+tid -> slot row r = j*64 + (tid>>2), phys
    // quad tid&3; logical quad = phys ^ (((r>>3)&1)<<1); bit3(r)=bit5(tid).
    const int rA = tid >> 2;
    const int qs = ((tid & 3) ^ (((tid >> 5) & 1) << 1)) * 8;
    const unsigned short* pa0 = Abase + (size_t)(rA      ) * DIM_IN + qs;
    const unsigned short* pa1 = Abase + (size_t)(rA +  64) * DIM_IN + qs;
    const unsigned short* pa2 = Abase + (size_t)(rA + 128) * DIM_IN + qs;
    const unsigned short* pa3 = Abase + (size_t)(rA + 192) * DIM_IN + qs;
    const unsigned short* pb0 = Bbase + (size_t)(rA      ) * DIM_IN + qs;
    const unsigned short* pb1 = Bbase + (size_t)(rA +  64) * DIM_IN + qs;

    // ds_read byte offset within a frag (row = 16*frag + l15; bit3(row)=bit3(l15))
    const int swb = ((l15 >> 3) & 1) << 1;
    const int lof = l15 * 64 + ((q16 ^ swb) << 4);

    f32x4 acc[8][4] = {};
    short8 af4[4], bfr[4];

#define STG_A(bs, k) do {                                                   \
        gload16(pa0 + (k), &LDS[bs][          wave * 512]);                 \
        gload16(pa1 + (k), &LDS[bs][2048 +    wave * 512]);                 \
        gload16(pa2 + (k), &LDS[bs][4096 +    wave * 512]);                 \
        gload16(pa3 + (k), &LDS[bs][6144 +    wave * 512]);                 \
    } while (0)

#define STG_B(bs, k) do {                                                   \
        gload16(pb0 + (k), &LDS[bs][8192 +         wave * 512]);            \
        gload16(pb1 + (k), &LDS[bs][8192 + 2048 + wave * 512]);             \
    } while (0)

#define RD_A4(b, mih) do {                                                  \
        const char* pA_ = (const char*)(&LDS[b][0])                         \
                          + (wr * 8 + (mih) * 4) * 1024 + lof;              \
        _Pragma("unroll")                                                   \
        for (int i_ = 0; i_ < 4; ++i_)                                      \
            af4[i_] = *reinterpret_cast<const short8*>(pA_ + 1024 * i_);    \
    } while (0)

#define RD_B4(b) do {                                                       \
        const char* pB_ = (const char*)(&LDS[b][0]) + 16384                 \
                          + wc * 4096 + lof;                                \
        _Pragma("unroll")                                                   \
        for (int i_ = 0; i_ < 4; ++i_)                                      \
            bfr[i_] = *reinterpret_cast<const short8*>(pB_ + 1024 * i_);    \
    } while (0)

#define MM(mih) do {                                                        \
        __builtin_amdgcn_s_setprio(1);                                      \
        _Pragma("unroll")                                                   \
        for (int i_ = 0; i_ < 4; ++i_) {                                    \
            _Pragma("unroll")                                               \
            for (int n_ = 0; n_ < 4; ++n_)                                  \
                acc[(mih)*4 + i_][n_] =                                     \
                    __builtin_amdgcn_mfma_f32_16x16x32_bf16(                \
                        af4[i_], bfr[n_], acc[(mih)*4 + i_][n_], 0, 0, 0);  \
        }                                                                   \
        __builtin_amdgcn_s_setprio(0);                                      \
    } while (0)

#define BAR   asm volatile("s_barrier" ::: "memory")
#define WAIT6 asm volatile("s_waitcnt vmcnt(6)" ::: "memory")

    // ---- prologue: stage tiles 0 and 1 ----
    STG_A(0, 0);  STG_B(0, 0);
    STG_A(1, 32); STG_B(1, 32);
    WAIT6;                        // tile0's 6 loads landed (per-wave)
    BAR;
    int kS = 64;

    // Tile t in buf b=t%3; stage tile t+2 into bs=(t+2)%3 (== (t-1)%3, whose
    // reads finished before t-1's end barrier). vmcnt(6) at tile end leaves
    // only this tile's 6 stage-loads outstanding -> tile t+1 fully landed.
#define TILE(b, bs) do {                                                    \
        STG_A(bs, kS);                                                      \
        RD_B4(b); RD_A4(b, 0); MM(0);                                       \
        STG_B(bs, kS); if (kS < 1504) kS += 32;                             \
        RD_A4(b, 1); MM(1);                                                 \
        WAIT6; BAR;                                                         \
    } while (0)

    #pragma unroll 1
    for (int i = 0; i < 16; ++i) {   // 48 K-tiles, 3 per iter
        TILE(0, 2);
        TILE(1, 0);
        TILE(2, 1);
    }

    // ---- epilogue: bias + store f32 ----
    const float* __restrict__ bptr = bias + (size_t)org * DIM_OUT;
    const int crow = q16 * 4;
    const int ccol = l15;
    #pragma unroll
    for (int ni = 0; ni < 4; ++ni) {
        const int gc = col0 + wc * 64 + ni * 16 + ccol;
        const float bv = bptr[gc];
        #pragma unroll
        for (int mi = 0; mi < 8; ++mi) {
            const int gr = row0 + wr * 128 + mi * 16 + crow;
            #pragma unroll
            for (int r = 0; r < 4; ++r)
                out[(size_t)(gr + r) * DIM_OUT + gc] = acc[mi][ni][r] + bv;
        }
    }
#undef STG_A
#undef STG_B
#undef RD_A4
#undef RD_B4
#undef MM
#undef BAR
#undef WAIT6
#undef TILE
}

// ---------- fallback (R2 kernel) if ws too small ----------
#define BM 128
#define BN 128
#define BK 32
#define LDK 40
union BF8 { unsigned short u[8]; short8 v; };

__global__ __launch_bounds__(256) void mol_gemm_fb(
    const float* __restrict__ x, const int* __restrict__ orgidx,
    const float* __restrict__ weight, const float* __restrict__ bias,
    float* __restrict__ out)
{
    __shared__ __align__(16) unsigned short Alds[2][BM][LDK];
    __shared__ __align__(16) unsigned short Blds[2][BN][LDK];

    const int tid  = threadIdx.x;
    const int lane = tid & 63;
    const int wave = tid >> 6;
    const int wr = wave >> 1, wc = wave & 1;

    const int bid = blockIdx.x;
    const int id  = (bid & 7) * 768 + (bid >> 3);
    const int row0 = (id / 24) * BM;
    const int col0 = (id % 24) * BN;

    const int batch = row0 / DIM_S;
    const int org   = orgidx[batch];
    const float* __restrict__ W = weight + (size_t)org * DIM_IN * DIM_OUT;

    f32x4 acc[4][4] = {};
    const int ar  = tid >> 2;
    const int ak8 = (tid & 3) * 8;
    const int bn  = tid & 127;
    const int bg0 = tid >> 7;
    const float* __restrict__ xbase = x + (size_t)row0 * DIM_IN;
    const float* __restrict__ wbase = W + col0 + bn;

    auto stage = [&](int buf, int k0) {
        #pragma unroll
        for (int i = 0; i < 2; ++i) {
            const int r = ar + 64 * i;
            const float* xp = xbase + (size_t)r * DIM_IN + k0 + ak8;
            const float4 v0 = *reinterpret_cast<const float4*>(xp);
            const float4 v1 = *reinterpret_cast<const float4*>(xp + 4);
            BF8 p;
            p.u[0] = f2bf(v0.x); p.u[1] = f2bf(v0.y);
            p.u[2] = f2bf(v0.z); p.u[3] = f2bf(v0.w);
            p.u[4] = f2bf(v1.x); p.u[5] = f2bf(v1.y);
            p.u[6] = f2bf(v1.z); p.u[7] = f2bf(v1.w);
            *reinterpret_cast<short8*>(&Alds[buf][r][ak8]) = p.v;
        }
        #pragma unroll
        for (int j = 0; j < 2; ++j) {
            const int g = bg0 + 2 * j;
            const float* wp = wbase + (size_t)(k0 + 8 * g) * DIM_OUT;
            BF8 p;
            #pragma unroll
            for (int r = 0; r < 8; ++r) p.u[r] = f2bf(wp[(size_t)r * DIM_OUT]);
            *reinterpret_cast<short8*>(&Blds[buf][bn][8 * g]) = p.v;
        }
    };

    stage(0, 0);
    const int nk = DIM_IN / BK;
    const int kq = (lane >> 4) * 8;
    const int lr = lane & 15;

    for (int t = 0; t < nk; ++t) {
        __syncthreads();
        const int cur = t & 1;
        if (t + 1 < nk) stage(cur ^ 1, (t + 1) * BK);
        short8 a[4], b[4];
        #pragma unroll
        for (int mi = 0; mi < 4; ++mi)
            a[mi] = *reinterpret_cast<const short8*>(&Alds[cur][wr * 64 + mi * 16 + lr][kq]);
        #pragma unroll
        for (int ni = 0; ni < 4; ++ni)
            b[ni] = *reinterpret_cast<const short8*>(&Blds[cur][wc * 64 + ni * 16 + lr][kq]);
        #pragma unroll
        for (int mi = 0; mi < 4; ++mi)
            #pragma unroll
            for (int ni = 0; ni < 4; ++ni)
                acc[mi][ni] = __builtin_amdgcn_mfma_f32_16x16x32_bf16(
                    a[mi], b[ni], acc[mi][ni], 0, 0, 0);
    }

    const float* __restrict__ bptr = bias + (size_t)org * DIM_OUT;
    const int crow = (lane >> 4) * 4;
    const int ccol = lane & 15;
    #pragma unroll
    for (int ni = 0; ni < 4; ++ni) {
        const int gc = col0 + wc * 64 + ni * 16 + ccol;
        const float bv = bptr[gc];
        #pragma unroll
        for (int mi = 0; mi < 4; ++mi) {
            const int gr = row0 + wr * 64 + mi * 16 + crow;
            #pragma unroll
            for (int r = 0; r < 4; ++r)
                out[(size_t)(gr + r) * DIM_OUT + gc] = acc[mi][ni][r] + bv;
        }
    }
}

extern "C" void kernel_launch(void* const* d_in, const int* in_sizes, int n_in,
                              void* d_out, int out_size, void* d_ws, size_t ws_size,
                              hipStream_t stream)
{
    const float* x      = (const float*)d_in[0];
    const int*   orgidx = (const int*)d_in[1];
    const float* weight = (const float*)d_in[2];
    const float* bias   = (const float*)d_in[3];
    float* out = (float*)d_out;

    if (ws_size >= WS_NEED) {
        unsigned short* xbp = (unsigned short*)d_ws;
        unsigned short* wtp = xbp + XB_ELEMS;
        cvt_x<<<dim3(2048), dim3(256), 0, stream>>>(x, xbp);
        cvt_wt<<<dim3(NORG * 24 * 48), dim3(256), 0, stream>>>(weight, wtp);
        mol_gemm_3b<<<dim3(3072), dim3(256), 0, stream>>>(xbp, orgidx, wtp, bias, out);
    } else {
        mol_gemm_fb<<<dim3(6144), dim3(256), 0, stream>>>(x, orgidx, weight, bias, out);
    }
}